// Round 18
// baseline (226.231 us; speedup 1.0000x reference)
//
#include <hip/hip_runtime.h>
#include <hip/hip_cooperative_groups.h>
#include <math.h>

namespace cg = cooperative_groups;

#define NEG_SLOPE 0.2f
#define NPAD 50176            // node capacity (multiple of 1024... 49*1024 = 50176)
#define NW8  (NPAD / 4)       // packed u32 cells (4 x u8 counts) = 12544
#define NCHUNK 128            // edge chunks == blocks of the cooperative CSR kernel

typedef _Float16 half4 __attribute__((ext_vector_type(4)));

// ================= cooperative CSR build: hist -> chscan -> rowptr -> place ==========
// 128 blocks x 1024 threads. Dynamic LDS: NW8 u32 (hist/cursors) + 1024 int (scan).
__global__ void k_csr(const int* __restrict__ dst, const int* __restrict__ src,
                      unsigned int* __restrict__ histw, float* __restrict__ dinv,
                      unsigned short* __restrict__ deg16, int* __restrict__ bsum,
                      int* __restrict__ rowptr, int* __restrict__ perm,
                      int e, int es, int n) {
    extern __shared__ unsigned int sbuf[];          // NW8 + 1024 u32
    int* ls = (int*)(sbuf + NW8);                   // 1024 ints
    __shared__ int ws2[20];
    cg::grid_group grid = cg::this_grid();
    int t = threadIdx.x;
    int b = blockIdx.x;

    // ---- phase 1: per-chunk histogram (LDS atomics, 4x u8 packed) ----
    for (int w = t; w < NW8; w += 1024) sbuf[w] = 0u;
    __syncthreads();
    int beg = b * es;
    int end = min(beg + es, e);
    for (int i = beg + t; i < end; i += 1024) {
        int d = dst[i];
        atomicAdd(&sbuf[d >> 2], 1u << ((d & 3) << 3));
    }
    __syncthreads();
    {
        unsigned int* out = histw + (size_t)b * NW8;
        for (int w = t; w < NW8; w += 1024) out[w] = sbuf[w];
    }
    grid.sync();

    // ---- phase 2: per-node exclusive scan over chunks (in place, u8); deg/dinv/bsum ----
    int i2 = b * 1024 + t;                          // blocks 0..48 cover NPAD exactly
    int deg = 0;
    if (i2 < NPAD) {
        unsigned char* p = (unsigned char*)histw + i2;
        unsigned int run = 0;
        for (int c = 0; c < NCHUNK; c += 8) {
            size_t bb = (size_t)c * NPAD;
            unsigned char v0 = p[bb];
            unsigned char v1 = p[bb + (size_t)1 * NPAD];
            unsigned char v2 = p[bb + (size_t)2 * NPAD];
            unsigned char v3 = p[bb + (size_t)3 * NPAD];
            unsigned char v4 = p[bb + (size_t)4 * NPAD];
            unsigned char v5 = p[bb + (size_t)5 * NPAD];
            unsigned char v6 = p[bb + (size_t)6 * NPAD];
            unsigned char v7 = p[bb + (size_t)7 * NPAD];
            unsigned int e0 = run;
            unsigned int e1 = e0 + v0;
            unsigned int e2 = e1 + v1;
            unsigned int e3 = e2 + v2;
            unsigned int e4 = e3 + v3;
            unsigned int e5 = e4 + v4;
            unsigned int e6 = e5 + v5;
            unsigned int e7 = e6 + v6;
            run = e7 + v7;
            p[bb] = (unsigned char)e0;
            p[bb + (size_t)1 * NPAD] = (unsigned char)e1;
            p[bb + (size_t)2 * NPAD] = (unsigned char)e2;
            p[bb + (size_t)3 * NPAD] = (unsigned char)e3;
            p[bb + (size_t)4 * NPAD] = (unsigned char)e4;
            p[bb + (size_t)5 * NPAD] = (unsigned char)e5;
            p[bb + (size_t)6 * NPAD] = (unsigned char)e6;
            p[bb + (size_t)7 * NPAD] = (unsigned char)e7;
        }
        deg = (int)run;
        if (i2 < n) dinv[i2] = rsqrtf((float)(deg + 1));  // +1 self-loop
        deg16[i2] = (unsigned short)deg;                  // zero beyond n
    }
    {
        int s = deg;
        for (int d = 1; d < 64; d <<= 1) s += __shfl_down(s, d);
        __syncthreads();                 // ls reuse safe (phase 1 done)
        if ((t & 63) == 0) ls[t >> 6] = s;
        __syncthreads();
        if (t == 0) {
            int s16 = 0;
            for (int w = 0; w < 16; ++w) s16 += ls[w];
            bsum[b] = s16;               // blocks >= 49 contribute 0
        }
    }
    grid.sync();

    // ---- phase 3: rowptr = boff(block prefix of bsum) + local 1024-scan ----
    if (t == 0) {
        int s = 0;
        for (int j = 0; j < b; ++j) s += bsum[j];
        ws2[0] = s;
    }
    int v3 = (i2 < n) ? (int)deg16[i2] : 0;
    ls[t] = v3;
    __syncthreads();
    for (int d = 1; d < 1024; d <<= 1) {
        int u = (t >= d) ? ls[t - d] : 0;
        __syncthreads();
        ls[t] += u;
        __syncthreads();
    }
    {
        int excl = ls[t] - v3 + ws2[0];
        if (i2 < n) rowptr[i2] = excl;
        if (i2 == n - 1) rowptr[n] = excl + v3;
    }
    grid.sync();

    // ---- phase 4: chunk-local place (LDS cursors = choff slice) ----
    {
        const unsigned int* in = histw + (size_t)b * NW8;
        for (int w = t; w < NW8; w += 1024) sbuf[w] = in[w];
        __syncthreads();
        for (int i = beg + t; i < end; i += 1024) {
            int d = dst[i];
            int sh = (d & 3) << 3;
            unsigned int old = atomicAdd(&sbuf[d >> 2], 1u << sh);
            int slot = rowptr[d] + (int)((old >> sh) & 0xffu);
            perm[slot] = src[i];
        }
    }
}

// ---------------- GEMM: [n,64] @ [64,64], epilogue * dinv[row], fp16 out ----------------
template <typename T>
__global__ __launch_bounds__(256) void k_gemm64(const T* __restrict__ in,
                                                const float* __restrict__ W,
                                                const float* __restrict__ dinv,
                                                _Float16* __restrict__ out, int n) {
    __shared__ float Ws[64 * 64];
    __shared__ float Xs[16 * 64];
    int t = threadIdx.x;
    const float4* W4 = (const float4*)W;
    float4* Ws4 = (float4*)Ws;
#pragma unroll
    for (int i = 0; i < 4; ++i) Ws4[t + 256 * i] = W4[t + 256 * i];
    int row0 = blockIdx.x * 16;
    {
        int r = t >> 4, c4 = t & 15;
        int row = row0 + r;
        float4 v = make_float4(0.f, 0.f, 0.f, 0.f);
        if (row < n) {
            if constexpr (sizeof(T) == 4) {
                v = ((const float4*)(in + (size_t)row * 64))[c4];
            } else {
                half4 hv = ((const half4*)(in + (size_t)row * 64))[c4];
                v = make_float4((float)hv.x, (float)hv.y, (float)hv.z, (float)hv.w);
            }
        }
        ((float4*)Xs)[t] = v;
    }
    __syncthreads();
    int c = t & 63, g = t >> 6;
    float a0 = 0.f, a1 = 0.f, a2 = 0.f, a3 = 0.f;
#pragma unroll
    for (int k = 0; k < 64; ++k) {
        float w = Ws[k * 64 + c];
        a0 = fmaf(Xs[g * 64 + k], w, a0);
        a1 = fmaf(Xs[(g + 4) * 64 + k], w, a1);
        a2 = fmaf(Xs[(g + 8) * 64 + k], w, a2);
        a3 = fmaf(Xs[(g + 12) * 64 + k], w, a3);
    }
    int r;
    r = row0 + g;      if (r < n) out[(size_t)r * 64 + c] = (_Float16)(a0 * dinv[r]);
    r = row0 + g + 4;  if (r < n) out[(size_t)r * 64 + c] = (_Float16)(a1 * dinv[r]);
    r = row0 + g + 8;  if (r < n) out[(size_t)r * 64 + c] = (_Float16)(a2 * dinv[r]);
    r = row0 + g + 12; if (r < n) out[(size_t)r * 64 + c] = (_Float16)(a3 * dinv[r]);
}

// ---------------- gather 64ch: fp16 rows (128B), wave per node, lane=channel, unroll 16 ----
// fuse == 0: write activated row as fp16 (feeds next gemm64).
// fuse != 0: project through W2 (64x4) via butterfly; write y[v] float4 (feeds gather4).
__global__ __launch_bounds__(256) void k_gather64(
        const _Float16* __restrict__ h, const float* __restrict__ dinv,
        const int* __restrict__ rowptr, const int* __restrict__ perm,
        const float* __restrict__ b, _Float16* __restrict__ out, int n, int act,
        const float* __restrict__ W2, float* __restrict__ y, int fuse) {
    int t = threadIdx.x;
    int v = blockIdx.x * 4 + (t >> 6);
    if (v >= n) return;
    v = __builtin_amdgcn_readfirstlane(v);  // SGPR: rowptr/perm -> scalar loads
    int lane = t & 63;
    const _Float16* hl = h + lane;
    float acc = (float)hl[(size_t)v * 64];
    int e = rowptr[v], end = rowptr[v + 1];
#define LOADK(j) float x##j = (float)hl[(size_t)perm[e + j] * 64]
    for (; e + 16 <= end; e += 16) {
        LOADK(0); LOADK(1); LOADK(2); LOADK(3);
        LOADK(4); LOADK(5); LOADK(6); LOADK(7);
        LOADK(8); LOADK(9); LOADK(10); LOADK(11);
        LOADK(12); LOADK(13); LOADK(14); LOADK(15);
        acc += (((x0 + x1) + (x2 + x3)) + ((x4 + x5) + (x6 + x7)))
             + (((x8 + x9) + (x10 + x11)) + ((x12 + x13) + (x14 + x15)));
    }
    if (e + 8 <= end) {
        LOADK(0); LOADK(1); LOADK(2); LOADK(3);
        LOADK(4); LOADK(5); LOADK(6); LOADK(7);
        acc += ((x0 + x1) + (x2 + x3)) + ((x4 + x5) + (x6 + x7));
        e += 8;
    }
    if (e + 4 <= end) {
        LOADK(0); LOADK(1); LOADK(2); LOADK(3);
        acc += (x0 + x1) + (x2 + x3);
        e += 4;
    }
    if (e + 2 <= end) {
        LOADK(0); LOADK(1);
        acc += x0 + x1;
        e += 2;
    }
    if (e < end) acc += (float)hl[(size_t)perm[e] * 64];
#undef LOADK
    float dv = dinv[v];
    acc = acc * dv + b[lane];
    if (act) acc = acc > 0.0f ? acc : acc * NEG_SLOPE;
    if (!fuse) {
        out[(size_t)v * 64 + lane] = (_Float16)acc;
    } else {
        // h2[c] = sum_k h1[k] * W2[k][c]; y[v] = h2 * dv
        float4 w = ((const float4*)W2)[lane];   // W2 row for this lane's channel
        float p0 = acc * w.x, p1 = acc * w.y, p2 = acc * w.z, p3 = acc * w.w;
#pragma unroll
        for (int dlt = 1; dlt < 64; dlt <<= 1) {
            p0 += __shfl_xor(p0, dlt);
            p1 += __shfl_xor(p1, dlt);
            p2 += __shfl_xor(p2, dlt);
            p3 += __shfl_xor(p3, dlt);
        }
        if (lane == 0)
            ((float4*)y)[v] = make_float4(p0 * dv, p1 * dv, p2 * dv, p3 * dv);
    }
}

// ---------------- gather 4ch: 4 lanes per node, fp32, unroll 4 ----------------
__global__ __launch_bounds__(256) void k_gather4(
        const float* __restrict__ h, const float* __restrict__ dinv,
        const int* __restrict__ rowptr, const int* __restrict__ perm,
        const float* __restrict__ b, float* __restrict__ out, int n) {
    int gid = blockIdx.x * 256 + threadIdx.x;
    int c = gid & 3;
    int v = gid >> 2;
    if (v >= n) return;
    const float* hc = h + c;
    float acc = hc[(size_t)v * 4];
    int e = rowptr[v], end = rowptr[v + 1];
    for (; e + 4 <= end; e += 4) {
        float x0 = hc[(size_t)perm[e] * 4];
        float x1 = hc[(size_t)perm[e + 1] * 4];
        float x2 = hc[(size_t)perm[e + 2] * 4];
        float x3 = hc[(size_t)perm[e + 3] * 4];
        acc += (x0 + x1) + (x2 + x3);
    }
    for (; e < end; ++e) acc += hc[(size_t)perm[e] * 4];
    out[(size_t)v * 4 + c] = acc * dinv[v] + b[c];
}

extern "C" void kernel_launch(void* const* d_in, const int* in_sizes, int n_in,
                              void* d_out, int out_size, void* d_ws, size_t ws_size,
                              hipStream_t stream) {
    const float* x  = (const float*)d_in[0];
    const int* ei   = (const int*)d_in[1];
    const float* W0 = (const float*)d_in[2];
    const float* b0 = (const float*)d_in[3];
    const float* W1 = (const float*)d_in[4];
    const float* b1 = (const float*)d_in[5];
    const float* W2 = (const float*)d_in[6];
    const float* b2 = (const float*)d_in[7];
    float* out = (float*)d_out;

    const int N = in_sizes[0] / 64;
    const int E = in_sizes[1] / 2;
    const int* src = ei;
    const int* dst = ei + E;
    const int es = (E + NCHUNK - 1) / NCHUNK;   // edges per chunk (6250)

    // workspace layout, 256B-aligned slabs
    char* base = (char*)d_ws;
    size_t off = 0;
    auto alloc = [&](size_t bytes) { size_t o = off; off = (off + bytes + 255) & ~(size_t)255; return o; };
    unsigned int*   histw  = (unsigned int*)(base + alloc((size_t)NCHUNK * NPAD));  // u8[C][NPAD] -> choff in place
    unsigned short* deg16  = (unsigned short*)(base + alloc((size_t)NPAD * 2));
    float*          dinv   = (float*)(base + alloc((size_t)NPAD * 4));
    int*            rowptr = (int*)(base + alloc((size_t)(NPAD + 1) * 4));
    int*            bsum   = (int*)(base + alloc(1024));
    int*            perm   = (int*)(base + alloc((size_t)E * 4));
    _Float16*       bufH   = (_Float16*)(base + alloc((size_t)N * 64 * 2));  // fp16 gather operand
    _Float16*       bufB16 = (_Float16*)(base + alloc((size_t)N * 64 * 2));  // fp16 act output (layer 0)
    float*          bufD   = (float*)(base + alloc((size_t)N * 4 * 4));      // fp32 y = (h1 W2) * dinv

    const int nb_V = (N + 3) / 4;       // wave per node, 4 per block

    // ---- CSR build + normalization: ONE cooperative kernel ----
    {
        int e_ = E, es_ = es, n_ = N;
        const int* dst_ = dst;
        const int* src_ = src;
        unsigned int* histw_ = histw;
        float* dinv_ = dinv;
        unsigned short* deg16_ = deg16;
        int* bsum_ = bsum;
        int* rowptr_ = rowptr;
        int* perm_ = perm;
        void* args[] = {(void*)&dst_, (void*)&src_, (void*)&histw_, (void*)&dinv_,
                        (void*)&deg16_, (void*)&bsum_, (void*)&rowptr_, (void*)&perm_,
                        (void*)&e_, (void*)&es_, (void*)&n_};
        size_t shmem = (size_t)(NW8 + 1024) * sizeof(unsigned int);
        hipLaunchCooperativeKernel((void*)k_csr, dim3(NCHUNK), dim3(1024),
                                   args, (unsigned int)shmem, stream);
    }

    // ---- layer 0 ----
    k_gemm64<float><<<(N + 15) / 16, 256, 0, stream>>>(x, W0, dinv, bufH, N);
    k_gather64<<<nb_V, 256, 0, stream>>>(bufH, dinv, rowptr, perm, b0, bufB16, N, 1,
                                         W2, bufD, 0);

    // ---- layer 1 (+ fused W2 projection) ----
    k_gemm64<_Float16><<<(N + 15) / 16, 256, 0, stream>>>(bufB16, W1, dinv, bufH, N);
    k_gather64<<<nb_V, 256, 0, stream>>>(bufH, dinv, rowptr, perm, b1, bufB16, N, 1,
                                         W2, bufD, 1);

    // ---- layer 2 (d_out = 4): aggregate y ----
    k_gather4<<<(N * 4 + 255) / 256, 256, 0, stream>>>(bufD, dinv, rowptr, perm, b2, out, N);
}

// Round 19
// 135.661 us; speedup vs baseline: 1.6676x; 1.6676x over previous
//
#include <hip/hip_runtime.h>
#include <math.h>

#define NEG_SLOPE 0.2f
#define NPAD 50176            // node capacity (multiple of 512)
#define NW8  (NPAD / 4)       // packed u32 cells (4 x u8 counts)
#define NCHUNK 128            // edge chunks == k_hist blocks (u8-safe: Poisson(0.125))

typedef _Float16 half4 __attribute__((ext_vector_type(4)));

// ---- phase 1: per-chunk histogram via LDS atomics (4x u8 packed) ----
__global__ __launch_bounds__(1024) void k_hist(const int* __restrict__ dst,
                                               unsigned int* __restrict__ histw,
                                               int e, int es) {
    extern __shared__ unsigned int lcnt[];  // NW8 u32 = 50176 B
    int t = threadIdx.x;
    for (int w = t; w < NW8; w += 1024) lcnt[w] = 0u;
    __syncthreads();
    int beg = blockIdx.x * es;
    int end = min(beg + es, e);
    for (int i = beg + t; i < end; i += 1024) {
        int d = dst[i];
        atomicAdd(&lcnt[d >> 2], 1u << ((d & 3) << 3));
    }
    __syncthreads();
    unsigned int* out = histw + (size_t)blockIdx.x * NW8;
    for (int w = t; w < NW8; w += 1024) out[w] = lcnt[w];
}

// ---- phase 2: per-node exclusive scan over chunks (in place, u8), deg/dinv/bsum ----
__global__ __launch_bounds__(256) void k_chscan(unsigned char* __restrict__ hist8,
                                                float* __restrict__ dinv,
                                                unsigned short* __restrict__ deg16,
                                                int* __restrict__ bsum, int n) {
    int t = threadIdx.x;
    int i = blockIdx.x * 256 + t;          // grid covers NPAD exactly
    unsigned char* p = hist8 + i;
    unsigned int run = 0;
    for (int c = 0; c < NCHUNK; c += 8) {
        size_t b = (size_t)c * NPAD;
        unsigned char v0 = p[b];
        unsigned char v1 = p[b + (size_t)1 * NPAD];
        unsigned char v2 = p[b + (size_t)2 * NPAD];
        unsigned char v3 = p[b + (size_t)3 * NPAD];
        unsigned char v4 = p[b + (size_t)4 * NPAD];
        unsigned char v5 = p[b + (size_t)5 * NPAD];
        unsigned char v6 = p[b + (size_t)6 * NPAD];
        unsigned char v7 = p[b + (size_t)7 * NPAD];
        unsigned int e0 = run;
        unsigned int e1 = e0 + v0;
        unsigned int e2 = e1 + v1;
        unsigned int e3 = e2 + v2;
        unsigned int e4 = e3 + v3;
        unsigned int e5 = e4 + v4;
        unsigned int e6 = e5 + v5;
        unsigned int e7 = e6 + v6;
        run = e7 + v7;
        p[b] = (unsigned char)e0;
        p[b + (size_t)1 * NPAD] = (unsigned char)e1;
        p[b + (size_t)2 * NPAD] = (unsigned char)e2;
        p[b + (size_t)3 * NPAD] = (unsigned char)e3;
        p[b + (size_t)4 * NPAD] = (unsigned char)e4;
        p[b + (size_t)5 * NPAD] = (unsigned char)e5;
        p[b + (size_t)6 * NPAD] = (unsigned char)e6;
        p[b + (size_t)7 * NPAD] = (unsigned char)e7;
    }
    int deg = (int)run;
    if (i < n) dinv[i] = rsqrtf((float)(deg + 1));  // +1 self-loop
    deg16[i] = (unsigned short)deg;                 // zero beyond n
    int s = deg;
    for (int d = 1; d < 64; d <<= 1) s += __shfl_down(s, d);
    __shared__ int ws[4];
    if ((t & 63) == 0) ws[t >> 6] = s;
    __syncthreads();
    if (t == 0) bsum[blockIdx.x] = ws[0] + ws[1] + ws[2] + ws[3];
}

// ---- phase 3: rowptr = global exclusive scan (block prefix of bsum + local scan) ----
__global__ __launch_bounds__(256) void k_scan3(const unsigned short* __restrict__ deg16,
                                               const int* __restrict__ bsum,
                                               int* __restrict__ rowptr, int n, int nb) {
    __shared__ int ls[256];
    __shared__ int wo[4];
    int t = threadIdx.x;
    int bid = blockIdx.x;
    int bv = (t < bid && t < nb) ? bsum[t] : 0;
    for (int d = 1; d < 64; d <<= 1) bv += __shfl_down(bv, d);
    if ((t & 63) == 0) wo[t >> 6] = bv;
    __syncthreads();
    int boff = wo[0] + wo[1] + wo[2] + wo[3];
    int i = bid * 256 + t;
    int v = (i < n) ? (int)deg16[i] : 0;
    ls[t] = v;
    __syncthreads();
    for (int d = 1; d < 256; d <<= 1) {
        int u = (t >= d) ? ls[t - d] : 0;
        __syncthreads();
        ls[t] += u;
        __syncthreads();
    }
    int excl = ls[t] - v + boff;
    if (i < n) rowptr[i] = excl;
    if (i == n - 1) rowptr[n] = excl + v;
}

// ---- phase 4: chunk-local place (LDS cursors, no rank array, no random choff reads) ----
__global__ __launch_bounds__(1024) void k_place2(const int* __restrict__ src,
                                                 const int* __restrict__ dst,
                                                 const int* __restrict__ rowptr,
                                                 const unsigned int* __restrict__ choffw,
                                                 int* __restrict__ perm, int e, int es) {
    extern __shared__ unsigned int cur[];  // NW8 u32 (4 x u8 cursors)
    int t = threadIdx.x;
    const unsigned int* in = choffw + (size_t)blockIdx.x * NW8;
    for (int w = t; w < NW8; w += 1024) cur[w] = in[w];
    __syncthreads();
    int beg = blockIdx.x * es;
    int end = min(beg + es, e);
    for (int i = beg + t; i < end; i += 1024) {
        int d = dst[i];
        int sh = (d & 3) << 3;
        unsigned int old = atomicAdd(&cur[d >> 2], 1u << sh);
        int slot = rowptr[d] + (int)((old >> sh) & 0xffu);
        perm[slot] = src[i];
    }
}

// ---------------- GEMM: [n,64] @ [64,64], epilogue * dinv[row], fp16 out ----------------
__global__ __launch_bounds__(256) void k_gemm64(const float* __restrict__ in,
                                                const float* __restrict__ W,
                                                const float* __restrict__ dinv,
                                                _Float16* __restrict__ out, int n) {
    __shared__ float Ws[64 * 64];
    __shared__ float Xs[16 * 64];
    int t = threadIdx.x;
    const float4* W4 = (const float4*)W;
    float4* Ws4 = (float4*)Ws;
#pragma unroll
    for (int i = 0; i < 4; ++i) Ws4[t + 256 * i] = W4[t + 256 * i];
    int row0 = blockIdx.x * 16;
    {
        int r = t >> 4, c4 = t & 15;
        int row = row0 + r;
        float4 v = make_float4(0.f, 0.f, 0.f, 0.f);
        if (row < n) v = ((const float4*)(in + (size_t)row * 64))[c4];
        ((float4*)Xs)[t] = v;
    }
    __syncthreads();
    int c = t & 63, g = t >> 6;
    float a0 = 0.f, a1 = 0.f, a2 = 0.f, a3 = 0.f;
#pragma unroll
    for (int k = 0; k < 64; ++k) {
        float w = Ws[k * 64 + c];
        a0 = fmaf(Xs[g * 64 + k], w, a0);
        a1 = fmaf(Xs[(g + 4) * 64 + k], w, a1);
        a2 = fmaf(Xs[(g + 8) * 64 + k], w, a2);
        a3 = fmaf(Xs[(g + 12) * 64 + k], w, a3);
    }
    int r;
    r = row0 + g;      if (r < n) out[(size_t)r * 64 + c] = (_Float16)(a0 * dinv[r]);
    r = row0 + g + 4;  if (r < n) out[(size_t)r * 64 + c] = (_Float16)(a1 * dinv[r]);
    r = row0 + g + 8;  if (r < n) out[(size_t)r * 64 + c] = (_Float16)(a2 * dinv[r]);
    r = row0 + g + 12; if (r < n) out[(size_t)r * 64 + c] = (_Float16)(a3 * dinv[r]);
}

// ---- fused layer-0 gather + layer-1 GEMM, 512 threads (8 waves, 8 nodes/block).
// VGPR cap at 512 thr = 256 (vs 64 at 1024 thr in the failed R16) -> no spill.
// Gather rows -> LDS fp32 -> barrier -> gemm64-shaped epilogue, fp16 out. ----
__global__ __launch_bounds__(512) void k_gather_gemm(
        const _Float16* __restrict__ h, const float* __restrict__ dinv,
        const int* __restrict__ rowptr, const int* __restrict__ perm,
        const float* __restrict__ b, const float* __restrict__ W,
        _Float16* __restrict__ out, int n) {
    __shared__ float Ws[64 * 64];
    __shared__ float Xs[8 * 64];
    int t = threadIdx.x;
    ((float4*)Ws)[t] = ((const float4*)W)[t];           // 512 x float4
    ((float4*)Ws)[t + 512] = ((const float4*)W)[t + 512];
    int row0 = blockIdx.x * 8;
    int wid = t >> 6;
    int lane = t & 63;
    int v = row0 + wid;
    if (v < n) {
        v = __builtin_amdgcn_readfirstlane(v);
        const _Float16* hl = h + lane;
        float acc = (float)hl[(size_t)v * 64];
        int e = rowptr[v], end = rowptr[v + 1];
#define LOADK(j) float x##j = (float)hl[(size_t)perm[e + j] * 64]
        for (; e + 16 <= end; e += 16) {
            LOADK(0); LOADK(1); LOADK(2); LOADK(3);
            LOADK(4); LOADK(5); LOADK(6); LOADK(7);
            LOADK(8); LOADK(9); LOADK(10); LOADK(11);
            LOADK(12); LOADK(13); LOADK(14); LOADK(15);
            acc += (((x0 + x1) + (x2 + x3)) + ((x4 + x5) + (x6 + x7)))
                 + (((x8 + x9) + (x10 + x11)) + ((x12 + x13) + (x14 + x15)));
        }
        if (e + 8 <= end) {
            LOADK(0); LOADK(1); LOADK(2); LOADK(3);
            LOADK(4); LOADK(5); LOADK(6); LOADK(7);
            acc += ((x0 + x1) + (x2 + x3)) + ((x4 + x5) + (x6 + x7));
            e += 8;
        }
        if (e + 4 <= end) {
            LOADK(0); LOADK(1); LOADK(2); LOADK(3);
            acc += (x0 + x1) + (x2 + x3);
            e += 4;
        }
        if (e + 2 <= end) {
            LOADK(0); LOADK(1);
            acc += x0 + x1;
            e += 2;
        }
        if (e < end) acc += (float)hl[(size_t)perm[e] * 64];
#undef LOADK
        float dv = dinv[v];
        acc = acc * dv + b[lane];
        acc = acc > 0.0f ? acc : acc * NEG_SLOPE;       // leaky relu
        Xs[wid * 64 + lane] = acc;                      // fp32, no extra rounding
    }
    __syncthreads();
    {
        int c = lane, g = wid;                           // row row0+g, col c
        float a0 = 0.f;
#pragma unroll
        for (int k = 0; k < 64; ++k)
            a0 = fmaf(Xs[g * 64 + k], Ws[k * 64 + c], a0);
        int r = row0 + g;
        if (r < n) out[(size_t)r * 64 + c] = (_Float16)(a0 * dinv[r]);
    }
}

// ---------------- gather 64ch (layer 1): fp16 rows, fused W2 projection -> y float4 ----
__global__ __launch_bounds__(256) void k_gather64(
        const _Float16* __restrict__ h, const float* __restrict__ dinv,
        const int* __restrict__ rowptr, const int* __restrict__ perm,
        const float* __restrict__ b, int n,
        const float* __restrict__ W2, float* __restrict__ y) {
    int t = threadIdx.x;
    int v = blockIdx.x * 4 + (t >> 6);
    if (v >= n) return;
    v = __builtin_amdgcn_readfirstlane(v);  // SGPR: rowptr/perm -> scalar loads
    int lane = t & 63;
    const _Float16* hl = h + lane;
    float acc = (float)hl[(size_t)v * 64];
    int e = rowptr[v], end = rowptr[v + 1];
#define LOADK(j) float x##j = (float)hl[(size_t)perm[e + j] * 64]
    for (; e + 16 <= end; e += 16) {
        LOADK(0); LOADK(1); LOADK(2); LOADK(3);
        LOADK(4); LOADK(5); LOADK(6); LOADK(7);
        LOADK(8); LOADK(9); LOADK(10); LOADK(11);
        LOADK(12); LOADK(13); LOADK(14); LOADK(15);
        acc += (((x0 + x1) + (x2 + x3)) + ((x4 + x5) + (x6 + x7)))
             + (((x8 + x9) + (x10 + x11)) + ((x12 + x13) + (x14 + x15)));
    }
    if (e + 8 <= end) {
        LOADK(0); LOADK(1); LOADK(2); LOADK(3);
        LOADK(4); LOADK(5); LOADK(6); LOADK(7);
        acc += ((x0 + x1) + (x2 + x3)) + ((x4 + x5) + (x6 + x7));
        e += 8;
    }
    if (e + 4 <= end) {
        LOADK(0); LOADK(1); LOADK(2); LOADK(3);
        acc += (x0 + x1) + (x2 + x3);
        e += 4;
    }
    if (e + 2 <= end) {
        LOADK(0); LOADK(1);
        acc += x0 + x1;
        e += 2;
    }
    if (e < end) acc += (float)hl[(size_t)perm[e] * 64];
#undef LOADK
    float dv = dinv[v];
    acc = acc * dv + b[lane];
    acc = acc > 0.0f ? acc : acc * NEG_SLOPE;
    float4 w = ((const float4*)W2)[lane];
    float p0 = acc * w.x, p1 = acc * w.y, p2 = acc * w.z, p3 = acc * w.w;
#pragma unroll
    for (int dlt = 1; dlt < 64; dlt <<= 1) {
        p0 += __shfl_xor(p0, dlt);
        p1 += __shfl_xor(p1, dlt);
        p2 += __shfl_xor(p2, dlt);
        p3 += __shfl_xor(p3, dlt);
    }
    if (lane == 0)
        ((float4*)y)[v] = make_float4(p0 * dv, p1 * dv, p2 * dv, p3 * dv);
}

// ---------------- gather 4ch: 4 lanes per node, fp32, unroll 4 ----------------
__global__ __launch_bounds__(256) void k_gather4(
        const float* __restrict__ h, const float* __restrict__ dinv,
        const int* __restrict__ rowptr, const int* __restrict__ perm,
        const float* __restrict__ b, float* __restrict__ out, int n) {
    int gid = blockIdx.x * 256 + threadIdx.x;
    int c = gid & 3;
    int v = gid >> 2;
    if (v >= n) return;
    const float* hc = h + c;
    float acc = hc[(size_t)v * 4];
    int e = rowptr[v], end = rowptr[v + 1];
    for (; e + 4 <= end; e += 4) {
        float x0 = hc[(size_t)perm[e] * 4];
        float x1 = hc[(size_t)perm[e + 1] * 4];
        float x2 = hc[(size_t)perm[e + 2] * 4];
        float x3 = hc[(size_t)perm[e + 3] * 4];
        acc += (x0 + x1) + (x2 + x3);
    }
    for (; e < end; ++e) acc += hc[(size_t)perm[e] * 4];
    out[(size_t)v * 4 + c] = acc * dinv[v] + b[c];
}

extern "C" void kernel_launch(void* const* d_in, const int* in_sizes, int n_in,
                              void* d_out, int out_size, void* d_ws, size_t ws_size,
                              hipStream_t stream) {
    const float* x  = (const float*)d_in[0];
    const int* ei   = (const int*)d_in[1];
    const float* W0 = (const float*)d_in[2];
    const float* b0 = (const float*)d_in[3];
    const float* W1 = (const float*)d_in[4];
    const float* b1 = (const float*)d_in[5];
    const float* W2 = (const float*)d_in[6];
    const float* b2 = (const float*)d_in[7];
    float* out = (float*)d_out;

    const int N = in_sizes[0] / 64;
    const int E = in_sizes[1] / 2;
    const int* src = ei;
    const int* dst = ei + E;
    const int es = (E + NCHUNK - 1) / NCHUNK;   // edges per chunk (6250)

    // workspace layout, 256B-aligned slabs
    char* base = (char*)d_ws;
    size_t off = 0;
    auto alloc = [&](size_t bytes) { size_t o = off; off = (off + bytes + 255) & ~(size_t)255; return o; };
    unsigned int*   histw  = (unsigned int*)(base + alloc((size_t)NCHUNK * NPAD));  // u8[C][NPAD] -> choff in place
    unsigned short* deg16  = (unsigned short*)(base + alloc((size_t)NPAD * 2));
    float*          dinv   = (float*)(base + alloc((size_t)NPAD * 4));
    int*            rowptr = (int*)(base + alloc((size_t)(NPAD + 1) * 4));
    int*            bsum   = (int*)(base + alloc(1024));
    int*            perm   = (int*)(base + alloc((size_t)E * 4));
    _Float16*       bufH   = (_Float16*)(base + alloc((size_t)N * 64 * 2));  // (xW0)*dinv fp16
    _Float16*       bufH2  = (_Float16*)(base + alloc((size_t)N * 64 * 2));  // (h1W1)*dinv fp16
    float*          bufD   = (float*)(base + alloc((size_t)N * 4 * 4));      // y = (h2 W2)*dinv fp32

    const int nb_N = (N + 255) / 256;   // 196
    const int nb_V = (N + 3) / 4;       // wave per node, 4 per block

    // ---- CSR build + normalization (no global atomics, no rank array) ----
    k_hist<<<NCHUNK, 1024, NW8 * sizeof(unsigned int), stream>>>(dst, histw, E, es);
    k_chscan<<<NPAD / 256, 256, 0, stream>>>((unsigned char*)histw, dinv, deg16, bsum, N);
    k_scan3<<<nb_N, 256, 0, stream>>>(deg16, bsum, rowptr, N, nb_N);
    k_place2<<<NCHUNK, 1024, NW8 * sizeof(unsigned int), stream>>>(src, dst, rowptr, histw, perm, E, es);

    // ---- layer 0 GEMM ----
    k_gemm64<<<(N + 15) / 16, 256, 0, stream>>>(x, W0, dinv, bufH, N);

    // ---- layer 0 gather + layer 1 GEMM (fused, 512 threads) ----
    k_gather_gemm<<<(N + 7) / 8, 512, 0, stream>>>(bufH, dinv, rowptr, perm, b0, W1, bufH2, N);

    // ---- layer 1 gather + fused W2 projection ----
    k_gather64<<<nb_V, 256, 0, stream>>>(bufH2, dinv, rowptr, perm, b1, N, W2, bufD);

    // ---- layer 2 (d_out = 4): aggregate y ----
    k_gather4<<<(N * 4 + 255) / 256, 256, 0, stream>>>(bufD, dinv, rowptr, perm, b2, out, N);
}